// Round 5
// baseline (217.325 us; speedup 1.0000x reference)
//
#include <hip/hip_runtime.h>
#include <hip/hip_bf16.h>
#include <math.h>

// Problem constants: B=8192, E=16, H=1024
#define B_SZ 8192
#define H_SZ 1024
#define E_SZ 16
#define NT   64          // 8192/128 panels
#define BM   128
#define SIM_THR 0.8f

typedef float floatx4 __attribute__((ext_vector_type(4)));

// ---------------- workspace layout ----------------
// 0: float gsum | 4: uint gcnt | 8: uint done
#define OFF_NE   4096
#define OFF_L    65536
#define OFF_P    (65536 + 524288)
#define OFF_EMB  2097152   // fp8 emb in MFMA-native layout: 8 MB

// MFMA-native fp8 layout: addr(r, k) = (r>>4)*16384 + (k>>6)*1024
//   + (((k>>5)&1))*512 + (((k>>3)&3))*128 + (r&15)*8 + (k&7)
// so a 16x16x32-fp8 A/B fragment load for rows [R,R+16), k-tile kt, half ks is
//   base + (R>>4)*16384 + kt*1024 + ks*512 + lane*8   (lane = q*16+m -> q*128+m*8)

// ---------------------------------------------------------------------------
// Fused prep: blocks 0..2047 normalize embeddings -> fp8 (MFMA-native layout);
// blocks 2048..2079 per-row log_softmax/softmax/neg-entropy + accum init.
// ---------------------------------------------------------------------------
__global__ void prep_kernel(const float* __restrict__ rp,
                            const float* __restrict__ emb,
                            unsigned char* __restrict__ out8,
                            float* __restrict__ L, float* __restrict__ P,
                            float* __restrict__ ne,
                            float* __restrict__ gsum, unsigned int* __restrict__ gcnt,
                            unsigned int* __restrict__ done) {
    const int b = blockIdx.x;
    if (b < 2048) {
        int r    = b * 4 + (threadIdx.x >> 6);   // one wave per row
        int lane = threadIdx.x & 63;
        const float4* row4 = (const float4*)(emb + (size_t)r * H_SZ);
        // lane owns floats k in [8*lane, 8*lane+8) and [512+8*lane, 512+8*lane+8)
        float4 a0 = row4[2 * lane], a1 = row4[2 * lane + 1];
        float4 b0 = row4[128 + 2 * lane], b1 = row4[129 + 2 * lane];
        float ss = a0.x*a0.x + a0.y*a0.y + a0.z*a0.z + a0.w*a0.w
                 + a1.x*a1.x + a1.y*a1.y + a1.z*a1.z + a1.w*a1.w
                 + b0.x*b0.x + b0.y*b0.y + b0.z*b0.z + b0.w*b0.w
                 + b1.x*b1.x + b1.y*b1.y + b1.z*b1.z + b1.w*b1.w;
#pragma unroll
        for (int off = 32; off > 0; off >>= 1) ss += __shfl_down(ss, off, 64);
        ss = __shfl(ss, 0, 64);
        float inv = rsqrtf(ss);
        // pack 8 floats -> 8 fp8 bytes (linear k order within the 8B chunk)
        unsigned int w0, w1;
        w0 = (unsigned int)__builtin_amdgcn_cvt_pk_fp8_f32(a0.x * inv, a0.y * inv, 0, false);
        w0 = (unsigned int)__builtin_amdgcn_cvt_pk_fp8_f32(a0.z * inv, a0.w * inv, w0, true);
        w1 = (unsigned int)__builtin_amdgcn_cvt_pk_fp8_f32(a1.x * inv, a1.y * inv, 0, false);
        w1 = (unsigned int)__builtin_amdgcn_cvt_pk_fp8_f32(a1.z * inv, a1.w * inv, w1, true);
        unsigned int w2, w3;
        w2 = (unsigned int)__builtin_amdgcn_cvt_pk_fp8_f32(b0.x * inv, b0.y * inv, 0, false);
        w2 = (unsigned int)__builtin_amdgcn_cvt_pk_fp8_f32(b0.z * inv, b0.w * inv, w2, true);
        w3 = (unsigned int)__builtin_amdgcn_cvt_pk_fp8_f32(b1.x * inv, b1.y * inv, 0, false);
        w3 = (unsigned int)__builtin_amdgcn_cvt_pk_fp8_f32(b1.z * inv, b1.w * inv, w3, true);
        // target: chunk0 at slot lane (kb=lane>>3, ks=(lane>>2)&1, q=lane&3),
        // chunk1 at +8KB (kb += 8), both with m = r&15
        size_t dst = (size_t)(r >> 4) * 16384
                   + (size_t)(lane >> 3) * 1024
                   + (size_t)((lane >> 2) & 1) * 512
                   + (size_t)(lane & 3) * 128
                   + (size_t)(r & 15) * 8;
        uint2 c0 = {w0, w1}, c1 = {w2, w3};
        *(uint2*)(out8 + dst)        = c0;
        *(uint2*)(out8 + dst + 8192) = c1;
    } else {
        int i = (b - 2048) * 256 + threadIdx.x;
        if (i == 0) { *gsum = 0.f; *gcnt = 0u; *done = 0u; }
        if (i >= B_SZ) return;
        const float* x = rp + i * E_SZ;
        float v[E_SZ];
        float m = -INFINITY;
#pragma unroll
        for (int k = 0; k < E_SZ; k++) { v[k] = x[k]; m = fmaxf(m, v[k]); }
        float s = 0.f;
#pragma unroll
        for (int k = 0; k < E_SZ; k++) s += expf(v[k] - m);
        float lse = m + logf(s);
        float nent = 0.f;
#pragma unroll
        for (int k = 0; k < E_SZ; k++) {
            float l = v[k] - lse;
            float p = expf(l);
            L[i * E_SZ + k] = l;
            P[i * E_SZ + k] = p;
            nent += p * l;
        }
        ne[i] = nent;
    }
}

// count of n in [lo,hi] with n&7==r; *first = smallest such n
__device__ __forceinline__ int cnt_range(int lo, int hi, int r, int* first) {
    int lo2 = lo + ((r - lo) & 7);
    *first = lo2;
    return (lo2 > hi) ? 0 : ((hi - lo2) >> 3) + 1;
}

__device__ __forceinline__ void load_frags(const char* pA, const char* pB, int kt,
                                           long* a, long* b) {
#pragma unroll
    for (int mi = 0; mi < 4; mi++)
#pragma unroll
        for (int ks = 0; ks < 2; ks++) {
            a[mi * 2 + ks] = *(const long*)(pA + mi * 16384 + kt * 1024 + ks * 512);
            b[mi * 2 + ks] = *(const long*)(pB + mi * 16384 + kt * 1024 + ks * 512);
        }
}

__device__ __forceinline__ void do_mfma(const long* a, const long* b, floatx4 acc[4][4]) {
#pragma unroll
    for (int ks = 0; ks < 2; ks++)
#pragma unroll
        for (int mi = 0; mi < 4; mi++)
#pragma unroll
            for (int ni = 0; ni < 4; ni++)
                acc[mi][ni] = __builtin_amdgcn_mfma_f32_16x16x32_fp8_fp8(
                    a[mi * 2 + ks], b[ni * 2 + ks], acc[mi][ni], 0, 0, 0);
}

// ---------------------------------------------------------------------------
// Main: fp8 MFMA sim tiles with fragments loaded DIRECTLY from global (L2-
// resident, MFMA-native layout) -- no LDS staging, no barriers in the K-loop.
// Owner-computes XCD partition kept. Epilogue: per-wave register-prefix
// compaction into a private LDS segment, dense processing, fused finalize.
// ---------------------------------------------------------------------------
__global__ __launch_bounds__(256)
void sim_kl_kernel(const unsigned char* __restrict__ embL,
                   const float* __restrict__ Lm, const float* __restrict__ Pm,
                   const float* __restrict__ ne,
                   float* __restrict__ gsum, unsigned int* __restrict__ gcnt,
                   unsigned int* __restrict__ done, float* __restrict__ out) {
    __shared__ unsigned short list[4][2048];   // 16 KB: per-wave private segments
    __shared__ float redf[4];
    __shared__ unsigned int redc[4];

    // --- blockIdx -> (bi, bj): XCD x owns bj panels with g(bj)==x ---
    const int x = blockIdx.x & 7;
    int s = blockIdx.x >> 3;            // 0..259
    int bi = 0, bj = 0;
    for (bi = 0; bi < NT; bi++) {
        int f1, f2;
        int n1 = (bi <= 31) ? cnt_range(bi, 31, x, &f1) : 0;
        int n2 = cnt_range(bi < 32 ? 32 : bi, 63, 7 - x, &f2);
        if (s < n1) { bj = f1 + 8 * s; break; }
        s -= n1;
        if (s < n2) { bj = f2 + 8 * s; break; }
        s -= n2;
    }
    const bool diag = (bi == bj);
    const int rowI = bi * BM, rowJ = bj * BM;

    const int tid  = threadIdx.x;
    const int lane = tid & 63;
    const int wave = tid >> 6;
    const int wr = (wave >> 1) * 64;
    const int wc = (wave & 1) * 64;
    const int quad = lane >> 4;
    const int l16  = lane & 15;

    floatx4 acc[4][4];
#pragma unroll
    for (int mi = 0; mi < 4; mi++)
#pragma unroll
        for (int ni = 0; ni < 4; ni++) {
            floatx4 z = {0.f, 0.f, 0.f, 0.f};
            acc[mi][ni] = z;
        }

    // fragment base pointers: wave-quadrant row-blocks, lane-linear within
    const char* pA = (const char*)embL + (size_t)(bi * 8 + (wave >> 1) * 4) * 16384 + lane * 8;
    const char* pB = (const char*)embL + (size_t)(bj * 8 + (wave & 1) * 4) * 16384 + lane * 8;

    // register double-buffered K-loop: 16 kt-steps of 64 fp8 elements
    long A0[8], B0[8], A1[8], B1[8];
    load_frags(pA, pB, 0, A0, B0);
#pragma unroll 1
    for (int kt = 0; kt < 16; kt += 2) {
        load_frags(pA, pB, kt + 1, A1, B1);
        do_mfma(A0, B0, acc);
        if (kt + 2 < 16) load_frags(pA, pB, kt + 2, A0, B0);
        do_mfma(A1, B1, acc);
    }

    // =================== per-wave compaction (no atomics/shfl) ==============
    unsigned short* wl = list[wave];
    int base = 0;
    // C/D layout: col = lane&15, row = quad*4 + reg
#pragma unroll
    for (int mi = 0; mi < 4; mi++) {
#pragma unroll
        for (int ni = 0; ni < 4; ni++) {
#pragma unroll
            for (int r = 0; r < 4; r++) {
                int il = wr + mi * 16 + quad * 4 + r;
                int jl = wc + ni * 16 + l16;
                bool msk = (acc[mi][ni][r] > SIM_THR) && (rowI + il != rowJ + jl);
                unsigned long long bal = __ballot(msk);
                if (msk) {
                    int pos = base + __popcll(bal & ((1ull << lane) - 1ull));
                    if (pos < 2048) wl[pos] = (unsigned short)((il << 8) | jl);
                }
                base += __popcll(bal);
            }
        }
    }
    if (base > 2048) base = 2048;   // safety clamp (expected ~32/wave)

    // =================== dense processing (wave-local) ======================
    float fsum = 0.f;
    unsigned int lcnt = 0;
    for (int t = lane; t < base; t += 64) {
        int e = wl[t];
        int i = rowI + (e >> 8), j = rowJ + (e & 255);
        const float4* Li4 = (const float4*)(Lm + i * E_SZ);
        const float4* Pj4 = (const float4*)(Pm + j * E_SZ);
        float d = 0.f;
#pragma unroll
        for (int q = 0; q < 4; q++) {
            float4 a = Li4[q], bb = Pj4[q];
            d += a.x * bb.x + a.y * bb.y + a.z * bb.z + a.w * bb.w;
        }
        float sv = ne[j] - d;
        unsigned int c = 1;
        if (!diag) {
            const float4* Lj4 = (const float4*)(Lm + j * E_SZ);
            const float4* Pi4 = (const float4*)(Pm + i * E_SZ);
            float d2 = 0.f;
#pragma unroll
            for (int q = 0; q < 4; q++) {
                float4 a = Lj4[q], bb = Pi4[q];
                d2 += a.x * bb.x + a.y * bb.y + a.z * bb.z + a.w * bb.w;
            }
            sv += ne[i] - d2;
            c = 2;
        }
        fsum += sv;
        lcnt += c;
    }

#pragma unroll
    for (int off = 32; off > 0; off >>= 1) {
        fsum += __shfl_down(fsum, off, 64);
        lcnt += __shfl_down(lcnt, off, 64);
    }
    if (lane == 0) { redf[wave] = fsum; redc[wave] = lcnt; }
    __syncthreads();
    if (tid == 0) {
        float sv = redf[0] + redf[1] + redf[2] + redf[3];
        unsigned int c = redc[0] + redc[1] + redc[2] + redc[3];
        if (c > 0u) {
            atomicAdd(gsum, sv);
            atomicAdd(gcnt, c);
        }
        __threadfence();                       // make accumulators visible
        unsigned int old = atomicAdd(done, 1u);
        if (old == gridDim.x - 1) {            // last block finalizes
            float S = atomicAdd(gsum, 0.0f);   // device-scope atomic read
            unsigned int C = atomicAdd(gcnt, 0u);
            out[0] = (C > 0u) ? (S / (float)C) : 0.f;   // WEIGHT = 1.0
        }
    }
}

// ---------------------------------------------------------------------------
extern "C" void kernel_launch(void* const* d_in, const int* in_sizes, int n_in,
                              void* d_out, int out_size, void* d_ws, size_t ws_size,
                              hipStream_t stream) {
    const float* rp  = (const float*)d_in[0];
    const float* emb = (const float*)d_in[1];
    float* out = (float*)d_out;

    char* ws = (char*)d_ws;
    float*         gsum = (float*)(ws + 0);
    unsigned int*  gcnt = (unsigned int*)(ws + 4);
    unsigned int*  done = (unsigned int*)(ws + 8);
    float*         ne   = (float*)(ws + OFF_NE);
    float*         Lm   = (float*)(ws + OFF_L);
    float*         Pm   = (float*)(ws + OFF_P);
    unsigned char* embL = (unsigned char*)(ws + OFF_EMB);

    prep_kernel<<<2048 + 32, 256, 0, stream>>>(rp, emb, embL, Lm, Pm, ne, gsum, gcnt, done);
    const int ntri = NT * (NT + 1) / 2;  // 2080
    sim_kl_kernel<<<ntri, 256, 0, stream>>>(embL, Lm, Pm, ne, gsum, gcnt, done, out);
}

// Round 6
// 195.537 us; speedup vs baseline: 1.1114x; 1.1114x over previous
//
#include <hip/hip_runtime.h>
#include <hip/hip_bf16.h>
#include <math.h>

// Problem constants: B=8192, E=16, H=1024
#define B_SZ 8192
#define H_SZ 1024
#define E_SZ 16
#define NT   64          // 8192/128 panels
#define BM   128
#define SIM_THR 0.8f

typedef float floatx4 __attribute__((ext_vector_type(4)));
typedef long  longx2  __attribute__((ext_vector_type(2)));

// ---------------- workspace layout ----------------
// 0: float gsum | 4: uint gcnt | 8: uint done
#define OFF_NE   4096
#define OFF_L    65536
#define OFF_P    (65536 + 524288)
#define OFF_EMB  2097152   // fp8 emb, MFMA-native 16B-chunk layout: 8 MB

// MFMA-native fp8 layout with PAIRED ks halves (16 B per lane-chunk):
// addr(r,k) = (r>>4)*16384 + (k>>6)*1024 + ((k>>3)&3)*256 + (r&15)*16
//           + ((k>>5)&1)*8 + (k&7)
// A 16x16x32 fragment for rows [G*16,G*16+16), k-window [kt*64+ks*32, +32):
//   one ds_read_b128 / global dwordx4 at G*16384 + kt*1024 + lane*16
//   yields ks=0 frag in .x and ks=1 frag in .y (longx2).

__device__ __forceinline__ void gload16(const void* g, void* l) {
    __builtin_amdgcn_global_load_lds(
        (const __attribute__((address_space(1))) void*)g,
        (__attribute__((address_space(3))) void*)l, 16, 0, 0);
}

// ---------------------------------------------------------------------------
// Fused prep: blocks 0..2047 normalize embeddings -> fp8 (MFMA-native layout);
// blocks 2048..2079 per-row log_softmax/softmax/neg-entropy + accum init.
// ---------------------------------------------------------------------------
__global__ void prep_kernel(const float* __restrict__ rp,
                            const float* __restrict__ emb,
                            unsigned char* __restrict__ out8,
                            float* __restrict__ L, float* __restrict__ P,
                            float* __restrict__ ne,
                            float* __restrict__ gsum, unsigned int* __restrict__ gcnt,
                            unsigned int* __restrict__ done) {
    const int b = blockIdx.x;
    if (b < 2048) {
        int r    = b * 4 + (threadIdx.x >> 6);   // one wave per row
        int lane = threadIdx.x & 63;
        int kt = lane >> 2, q = lane & 3;
        const float4* row4 = (const float4*)(emb + (size_t)r * H_SZ);
        int f0 = (kt * 64 + q * 8) >> 2;         // float4 index of ks=0 chunk
        float4 a0 = row4[f0],     a1 = row4[f0 + 1];   // ks=0: 8 floats
        float4 b0 = row4[f0 + 8], b1 = row4[f0 + 9];   // ks=1: +32 floats
        float ss = a0.x*a0.x + a0.y*a0.y + a0.z*a0.z + a0.w*a0.w
                 + a1.x*a1.x + a1.y*a1.y + a1.z*a1.z + a1.w*a1.w
                 + b0.x*b0.x + b0.y*b0.y + b0.z*b0.z + b0.w*b0.w
                 + b1.x*b1.x + b1.y*b1.y + b1.z*b1.z + b1.w*b1.w;
#pragma unroll
        for (int off = 32; off > 0; off >>= 1) ss += __shfl_down(ss, off, 64);
        ss = __shfl(ss, 0, 64);
        float inv = rsqrtf(ss);
        unsigned int w0, w1, w2, w3;
        w0 = (unsigned int)__builtin_amdgcn_cvt_pk_fp8_f32(a0.x * inv, a0.y * inv, 0, false);
        w0 = (unsigned int)__builtin_amdgcn_cvt_pk_fp8_f32(a0.z * inv, a0.w * inv, w0, true);
        w1 = (unsigned int)__builtin_amdgcn_cvt_pk_fp8_f32(a1.x * inv, a1.y * inv, 0, false);
        w1 = (unsigned int)__builtin_amdgcn_cvt_pk_fp8_f32(a1.z * inv, a1.w * inv, w1, true);
        w2 = (unsigned int)__builtin_amdgcn_cvt_pk_fp8_f32(b0.x * inv, b0.y * inv, 0, false);
        w2 = (unsigned int)__builtin_amdgcn_cvt_pk_fp8_f32(b0.z * inv, b0.w * inv, w2, true);
        w3 = (unsigned int)__builtin_amdgcn_cvt_pk_fp8_f32(b1.x * inv, b1.y * inv, 0, false);
        w3 = (unsigned int)__builtin_amdgcn_cvt_pk_fp8_f32(b1.z * inv, b1.w * inv, w3, true);
        size_t dst = (size_t)(r >> 4) * 16384 + (size_t)kt * 1024
                   + (size_t)q * 256 + (size_t)(r & 15) * 16;
        uint4 c = {w0, w1, w2, w3};   // [ks0: 8B][ks1: 8B]
        *(uint4*)(out8 + dst) = c;
    } else {
        int i = (b - 2048) * 256 + threadIdx.x;
        if (i == 0) { *gsum = 0.f; *gcnt = 0u; *done = 0u; }
        if (i >= B_SZ) return;
        const float* x = rp + i * E_SZ;
        float v[E_SZ];
        float m = -INFINITY;
#pragma unroll
        for (int k = 0; k < E_SZ; k++) { v[k] = x[k]; m = fmaxf(m, v[k]); }
        float s = 0.f;
#pragma unroll
        for (int k = 0; k < E_SZ; k++) s += expf(v[k] - m);
        float lse = m + logf(s);
        float nent = 0.f;
#pragma unroll
        for (int k = 0; k < E_SZ; k++) {
            float l = v[k] - lse;
            float p = expf(l);
            L[i * E_SZ + k] = l;
            P[i * E_SZ + k] = p;
            nent += p * l;
        }
        ne[i] = nent;
    }
}

// count of n in [lo,hi] with n&7==r; *first = smallest such n
__device__ __forceinline__ int cnt_range(int lo, int hi, int r, int* first) {
    int lo2 = lo + ((r - lo) & 7);
    *first = lo2;
    return (lo2 > hi) ? 0 : ((hi - lo2) >> 3) + 1;
}

// ---------------------------------------------------------------------------
// Main: fp8 MFMA sim tiles. Staging: global_load_lds dwordx4 of contiguous
// 1-KB MFMA-native groups (layout-preserving), LDS double-buffer, ONE barrier
// per K-step. Fragments: 8x ds_read_b128 at base+lane*16 (conflict-free),
// each read yields both ks halves. Owner-computes XCD partition. Per-wave
// compaction epilogue + fused finalize.
// ---------------------------------------------------------------------------
__global__ __launch_bounds__(256)
void sim_kl_kernel(const unsigned char* __restrict__ embL,
                   const float* __restrict__ Lm, const float* __restrict__ Pm,
                   const float* __restrict__ ne,
                   float* __restrict__ gsum, unsigned int* __restrict__ gcnt,
                   unsigned int* __restrict__ done, float* __restrict__ out) {
    __shared__ __align__(16) char As[2][8192];   // 8 groups x 1 KB per buffer
    __shared__ __align__(16) char Bs[2][8192];
    __shared__ float redf[4];
    __shared__ unsigned int redc[4];

    // --- blockIdx -> (bi, bj): XCD x owns bj panels with g(bj)==x ---
    const int x = blockIdx.x & 7;
    int s = blockIdx.x >> 3;            // 0..259
    int bi = 0, bj = 0;
    for (bi = 0; bi < NT; bi++) {
        int f1, f2;
        int n1 = (bi <= 31) ? cnt_range(bi, 31, x, &f1) : 0;
        int n2 = cnt_range(bi < 32 ? 32 : bi, 63, 7 - x, &f2);
        if (s < n1) { bj = f1 + 8 * s; break; }
        s -= n1;
        if (s < n2) { bj = f2 + 8 * s; break; }
        s -= n2;
    }
    const bool diag = (bi == bj);
    const int rowI = bi * BM, rowJ = bj * BM;

    const int tid  = threadIdx.x;
    const int lane = tid & 63;
    const int wave = tid >> 6;
    const int wr = (wave >> 1) * 64;
    const int wc = (wave & 1) * 64;
    const int quad = lane >> 4;
    const int l16  = lane & 15;

    floatx4 acc[4][4];
#pragma unroll
    for (int mi = 0; mi < 4; mi++)
#pragma unroll
        for (int ni = 0; ni < 4; ni++) {
            floatx4 z = {0.f, 0.f, 0.f, 0.f};
            acc[mi][ni] = z;
        }

    // staging: wave w stages groups {2w, 2w+1} of A and B (1 KB each, lane*16)
    const char* srcA = (const char*)embL + (size_t)(bi * 8 + 2 * wave) * 16384 + lane * 16;
    const char* srcB = (const char*)embL + (size_t)(bj * 8 + 2 * wave) * 16384 + lane * 16;
    const int gOff = 2 * wave * 1024;   // wave-uniform LDS group offset

    {   // prologue: stage kt=0 into buffer 0
        gload16(srcA,         As[0] + gOff);
        gload16(srcA + 16384, As[0] + gOff + 1024);
        gload16(srcB,         Bs[0] + gOff);
        gload16(srcB + 16384, Bs[0] + gOff + 1024);
    }

    // fragment LDS offsets (wave-uniform group + lane*16)
    const int aoff = (wr >> 4) * 1024 + lane * 16;   // + mi*1024
    const int boff = (wc >> 4) * 1024 + lane * 16;   // + ni*1024

    for (int kt = 0; kt < 16; kt++) {
        const int b = kt & 1;
        __syncthreads();                 // vmcnt(0)+barrier: buffer b ready
        if (kt + 1 < 16) {               // prefetch kt+1; overlaps MFMAs below
            const int ko = (kt + 1) * 1024;
            gload16(srcA + ko,         As[b ^ 1] + gOff);
            gload16(srcA + ko + 16384, As[b ^ 1] + gOff + 1024);
            gload16(srcB + ko,         Bs[b ^ 1] + gOff);
            gload16(srcB + ko + 16384, Bs[b ^ 1] + gOff + 1024);
        }

        longx2 af[4], bfm[4];
#pragma unroll
        for (int mi = 0; mi < 4; mi++)
            af[mi] = *(const longx2*)(As[b] + aoff + mi * 1024);
#pragma unroll
        for (int ni = 0; ni < 4; ni++)
            bfm[ni] = *(const longx2*)(Bs[b] + boff + ni * 1024);
#pragma unroll
        for (int mi = 0; mi < 4; mi++)
#pragma unroll
            for (int ni = 0; ni < 4; ni++) {
                acc[mi][ni] = __builtin_amdgcn_mfma_f32_16x16x32_fp8_fp8(
                    af[mi].x, bfm[ni].x, acc[mi][ni], 0, 0, 0);
                acc[mi][ni] = __builtin_amdgcn_mfma_f32_16x16x32_fp8_fp8(
                    af[mi].y, bfm[ni].y, acc[mi][ni], 0, 0, 0);
            }
    }

    // =================== per-wave compaction epilogue =======================
    __syncthreads();                 // all tile reads done: overlay list on As
    unsigned short* wl = (unsigned short*)As + wave * 2048;
    int base = 0;
    // C/D layout: col = lane&15, row = quad*4 + reg
#pragma unroll
    for (int mi = 0; mi < 4; mi++) {
#pragma unroll
        for (int ni = 0; ni < 4; ni++) {
#pragma unroll
            for (int r = 0; r < 4; r++) {
                int il = wr + mi * 16 + quad * 4 + r;
                int jl = wc + ni * 16 + l16;
                bool msk = (acc[mi][ni][r] > SIM_THR) && (rowI + il != rowJ + jl);
                unsigned long long bal = __ballot(msk);
                if (msk) {
                    int pos = base + __popcll(bal & ((1ull << lane) - 1ull));
                    if (pos < 2048) wl[pos] = (unsigned short)((il << 8) | jl);
                }
                base += __popcll(bal);
            }
        }
    }
    if (base > 2048) base = 2048;   // safety clamp (expected ~32/wave)

    float fsum = 0.f;
    unsigned int lcnt = 0;
    for (int t = lane; t < base; t += 64) {
        int e = wl[t];
        int i = rowI + (e >> 8), j = rowJ + (e & 255);
        const float4* Li4 = (const float4*)(Lm + i * E_SZ);
        const float4* Pj4 = (const float4*)(Pm + j * E_SZ);
        float d = 0.f;
#pragma unroll
        for (int q = 0; q < 4; q++) {
            float4 a = Li4[q], bb = Pj4[q];
            d += a.x * bb.x + a.y * bb.y + a.z * bb.z + a.w * bb.w;
        }
        float sv = ne[j] - d;
        unsigned int c = 1;
        if (!diag) {
            const float4* Lj4 = (const float4*)(Lm + j * E_SZ);
            const float4* Pi4 = (const float4*)(Pm + i * E_SZ);
            float d2 = 0.f;
#pragma unroll
            for (int q = 0; q < 4; q++) {
                float4 a = Lj4[q], bb = Pi4[q];
                d2 += a.x * bb.x + a.y * bb.y + a.z * bb.z + a.w * bb.w;
            }
            sv += ne[i] - d2;
            c = 2;
        }
        fsum += sv;
        lcnt += c;
    }

#pragma unroll
    for (int off = 32; off > 0; off >>= 1) {
        fsum += __shfl_down(fsum, off, 64);
        lcnt += __shfl_down(lcnt, off, 64);
    }
    if (lane == 0) { redf[wave] = fsum; redc[wave] = lcnt; }
    __syncthreads();
    if (tid == 0) {
        float sv = redf[0] + redf[1] + redf[2] + redf[3];
        unsigned int c = redc[0] + redc[1] + redc[2] + redc[3];
        if (c > 0u) {
            atomicAdd(gsum, sv);
            atomicAdd(gcnt, c);
        }
        __threadfence();                       // make accumulators visible
        unsigned int old = atomicAdd(done, 1u);
        if (old == gridDim.x - 1) {            // last block finalizes
            float S = atomicAdd(gsum, 0.0f);   // device-scope atomic read
            unsigned int C = atomicAdd(gcnt, 0u);
            out[0] = (C > 0u) ? (S / (float)C) : 0.f;   // WEIGHT = 1.0
        }
    }
}

// ---------------------------------------------------------------------------
extern "C" void kernel_launch(void* const* d_in, const int* in_sizes, int n_in,
                              void* d_out, int out_size, void* d_ws, size_t ws_size,
                              hipStream_t stream) {
    const float* rp  = (const float*)d_in[0];
    const float* emb = (const float*)d_in[1];
    float* out = (float*)d_out;

    char* ws = (char*)d_ws;
    float*         gsum = (float*)(ws + 0);
    unsigned int*  gcnt = (unsigned int*)(ws + 4);
    unsigned int*  done = (unsigned int*)(ws + 8);
    float*         ne   = (float*)(ws + OFF_NE);
    float*         Lm   = (float*)(ws + OFF_L);
    float*         Pm   = (float*)(ws + OFF_P);
    unsigned char* embL = (unsigned char*)(ws + OFF_EMB);

    prep_kernel<<<2048 + 32, 256, 0, stream>>>(rp, emb, embL, Lm, Pm, ne, gsum, gcnt, done);
    const int ntri = NT * (NT + 1) / 2;  // 2080
    sim_kl_kernel<<<ntri, 256, 0, stream>>>(embL, Lm, Pm, ne, gsum, gcnt, done, out);
}

// Round 7
// 174.206 us; speedup vs baseline: 1.2475x; 1.1224x over previous
//
#include <hip/hip_runtime.h>
#include <hip/hip_bf16.h>
#include <math.h>

// Problem constants: B=8192, E=16, H=1024
#define B_SZ 8192
#define H_SZ 1024
#define E_SZ 16
#define SIM_THR 0.8f

typedef float floatx4 __attribute__((ext_vector_type(4)));
typedef long  longx2  __attribute__((ext_vector_type(2)));

// ---------------- workspace layout ----------------
// 0: float gsum | 4: uint gcnt | 8: uint done
#define OFF_NE   4096
#define OFF_L    65536
#define OFF_P    (65536 + 524288)
#define OFF_EMB  2097152   // fp8 emb, MFMA-native 16B-chunk layout: 8 MB

// MFMA-native fp8 layout with PAIRED ks halves (16 B per lane-chunk):
// addr(r,k) = (r>>4)*16384 + (k>>6)*1024 + ((k>>3)&3)*256 + (r&15)*16
//           + ((k>>5)&1)*8 + (k&7)
// One ds_read_b128 / dwordx4 at group*16384 + kt*1024 + lane*16 yields the
// 16x16x32 fragment for ks=0 in .x and ks=1 in .y (longx2).

__device__ __forceinline__ void gload16(const void* g, void* l) {
    __builtin_amdgcn_global_load_lds(
        (const __attribute__((address_space(1))) void*)g,
        (__attribute__((address_space(3))) void*)l, 16, 0, 0);
}

// ---------------------------------------------------------------------------
// Fused prep: blocks 0..2047 normalize embeddings -> fp8 (MFMA-native layout);
// blocks 2048..2079 per-row log_softmax/softmax/neg-entropy + accum init.
// ---------------------------------------------------------------------------
__global__ void prep_kernel(const float* __restrict__ rp,
                            const float* __restrict__ emb,
                            unsigned char* __restrict__ out8,
                            float* __restrict__ L, float* __restrict__ P,
                            float* __restrict__ ne,
                            float* __restrict__ gsum, unsigned int* __restrict__ gcnt,
                            unsigned int* __restrict__ done) {
    const int b = blockIdx.x;
    if (b < 2048) {
        int r    = b * 4 + (threadIdx.x >> 6);   // one wave per row
        int lane = threadIdx.x & 63;
        int kt = lane >> 2, q = lane & 3;
        const float4* row4 = (const float4*)(emb + (size_t)r * H_SZ);
        int f0 = (kt * 64 + q * 8) >> 2;         // float4 index of ks=0 chunk
        float4 a0 = row4[f0],     a1 = row4[f0 + 1];   // ks=0: 8 floats
        float4 b0 = row4[f0 + 8], b1 = row4[f0 + 9];   // ks=1: +32 floats
        float ss = a0.x*a0.x + a0.y*a0.y + a0.z*a0.z + a0.w*a0.w
                 + a1.x*a1.x + a1.y*a1.y + a1.z*a1.z + a1.w*a1.w
                 + b0.x*b0.x + b0.y*b0.y + b0.z*b0.z + b0.w*b0.w
                 + b1.x*b1.x + b1.y*b1.y + b1.z*b1.z + b1.w*b1.w;
#pragma unroll
        for (int off = 32; off > 0; off >>= 1) ss += __shfl_down(ss, off, 64);
        ss = __shfl(ss, 0, 64);
        float inv = rsqrtf(ss);
        unsigned int w0, w1, w2, w3;
        w0 = (unsigned int)__builtin_amdgcn_cvt_pk_fp8_f32(a0.x * inv, a0.y * inv, 0, false);
        w0 = (unsigned int)__builtin_amdgcn_cvt_pk_fp8_f32(a0.z * inv, a0.w * inv, w0, true);
        w1 = (unsigned int)__builtin_amdgcn_cvt_pk_fp8_f32(a1.x * inv, a1.y * inv, 0, false);
        w1 = (unsigned int)__builtin_amdgcn_cvt_pk_fp8_f32(a1.z * inv, a1.w * inv, w1, true);
        w2 = (unsigned int)__builtin_amdgcn_cvt_pk_fp8_f32(b0.x * inv, b0.y * inv, 0, false);
        w2 = (unsigned int)__builtin_amdgcn_cvt_pk_fp8_f32(b0.z * inv, b0.w * inv, w2, true);
        w3 = (unsigned int)__builtin_amdgcn_cvt_pk_fp8_f32(b1.x * inv, b1.y * inv, 0, false);
        w3 = (unsigned int)__builtin_amdgcn_cvt_pk_fp8_f32(b1.z * inv, b1.w * inv, w3, true);
        size_t dst = (size_t)(r >> 4) * 16384 + (size_t)kt * 1024
                   + (size_t)q * 256 + (size_t)(r & 15) * 16;
        uint4 c = {w0, w1, w2, w3};   // [ks0: 8B][ks1: 8B]
        *(uint4*)(out8 + dst) = c;
    } else {
        int i = (b - 2048) * 256 + threadIdx.x;
        if (i == 0) { *gsum = 0.f; *gcnt = 0u; *done = 0u; }
        if (i >= B_SZ) return;
        const float* x = rp + i * E_SZ;
        float v[E_SZ];
        float m = -INFINITY;
#pragma unroll
        for (int k = 0; k < E_SZ; k++) { v[k] = x[k]; m = fmaxf(m, v[k]); }
        float s = 0.f;
#pragma unroll
        for (int k = 0; k < E_SZ; k++) s += expf(v[k] - m);
        float lse = m + logf(s);
        float nent = 0.f;
#pragma unroll
        for (int k = 0; k < E_SZ; k++) {
            float l = v[k] - lse;
            float p = expf(l);
            L[i * E_SZ + k] = l;
            P[i * E_SZ + k] = p;
            nent += p * l;
        }
        ne[i] = nent;
    }
}

// count of n in [lo,hi] with n&7==r; *first = smallest such n
__device__ __forceinline__ int cnt_range(int lo, int hi, int r, int* first) {
    int lo2 = lo + ((r - lo) & 7);
    *first = lo2;
    return (lo2 > hi) ? 0 : ((hi - lo2) >> 3) + 1;
}

// ---------------------------------------------------------------------------
// Main: 256x128 fp8 MFMA sim tiles (512 threads, 8 waves), halving the number
// of barrier-synchronized staging rounds vs 128x128. Staging: 3 gload16/wave
// per K-step (16 A-groups + 8 B-groups of 1 KB), LDS double-buffer, one
// barrier per K-step. Strict j>i pair rule (both KL directions, cnt+=2).
// Owner-computes XCD partition on bj; over-provisioned grid w/ early exit.
// ---------------------------------------------------------------------------
#define GRID_PER_XCD 164
__global__ __launch_bounds__(512, 4)
void sim_kl_kernel(const unsigned char* __restrict__ embL,
                   const float* __restrict__ Lm, const float* __restrict__ Pm,
                   const float* __restrict__ ne,
                   float* __restrict__ gsum, unsigned int* __restrict__ gcnt,
                   unsigned int* __restrict__ done, float* __restrict__ out) {
    __shared__ __align__(16) char As[2][16384];  // 16 groups x 1 KB per buffer
    __shared__ __align__(16) char Bs[2][8192];   //  8 groups x 1 KB per buffer
    __shared__ float redf[8];
    __shared__ unsigned int redc[8];

    // --- blockIdx -> (BI, bj): XCD x owns bj panels with class(bj)==x ---
    const int x = blockIdx.x & 7;
    int s = blockIdx.x >> 3;            // slot within this XCD's tile list
    int BI = 0, bj = 0;
    bool have = false;
    for (BI = 0; BI < 32; BI++) {
        int lo = 2 * BI, f1, f2;
        int n1 = (lo <= 31) ? cnt_range(lo, 31, x, &f1) : 0;
        int n2 = cnt_range(lo < 32 ? 32 : lo, 63, 7 - x, &f2);
        if (s < n1) { bj = f1 + 8 * s; have = true; break; }
        s -= n1;
        if (s < n2) { bj = f2 + 8 * s; have = true; break; }
        s -= n2;
    }

    const int tid  = threadIdx.x;
    const int lane = tid & 63;
    const int wave = tid >> 6;

    float fsum = 0.f;
    unsigned int lcnt = 0;

    if (have) {
        const int rowI = BI * 256, rowJ = bj * 128;
        const int wrg = (wave >> 1);        // A row-group quadrant 0..3 (x64 rows)
        const int wcg = (wave & 1);         // B col-group 0..1 (x64 cols)
        const int quad = lane >> 4;
        const int l16  = lane & 15;

        floatx4 acc[4][4];
#pragma unroll
        for (int mi = 0; mi < 4; mi++)
#pragma unroll
            for (int ni = 0; ni < 4; ni++) {
                floatx4 z = {0.f, 0.f, 0.f, 0.f};
                acc[mi][ni] = z;
            }

        // staging: wave stages A groups {2w,2w+1} and B group {w} (1 KB each)
        const char* srcA = (const char*)embL + (size_t)(BI * 16 + 2 * wave) * 16384 + lane * 16;
        const char* srcB = (const char*)embL + (size_t)(bj * 8 + wave) * 16384 + lane * 16;
        const int aW = 2 * wave * 1024;     // wave-uniform LDS offsets
        const int bW = wave * 1024;

        {   // prologue: stage kt=0 into buffer 0
            gload16(srcA,         As[0] + aW);
            gload16(srcA + 16384, As[0] + aW + 1024);
            gload16(srcB,         Bs[0] + bW);
        }

        const int aoff = wrg * 4096 + lane * 16;   // + mi*1024
        const int boff = wcg * 4096 + lane * 16;   // + ni*1024

        for (int kt = 0; kt < 16; kt++) {
            const int b = kt & 1;
            __syncthreads();                 // vmcnt drain + barrier: buffer b ready
            if (kt + 1 < 16) {               // prefetch kt+1; overlaps MFMAs below
                const int ko = (kt + 1) * 1024;
                gload16(srcA + ko,         As[b ^ 1] + aW);
                gload16(srcA + ko + 16384, As[b ^ 1] + aW + 1024);
                gload16(srcB + ko,         Bs[b ^ 1] + bW);
            }

            longx2 af[4], bfm[4];
#pragma unroll
            for (int mi = 0; mi < 4; mi++)
                af[mi] = *(const longx2*)(As[b] + aoff + mi * 1024);
#pragma unroll
            for (int ni = 0; ni < 4; ni++)
                bfm[ni] = *(const longx2*)(Bs[b] + boff + ni * 1024);
#pragma unroll
            for (int mi = 0; mi < 4; mi++)
#pragma unroll
                for (int ni = 0; ni < 4; ni++) {
                    acc[mi][ni] = __builtin_amdgcn_mfma_f32_16x16x32_fp8_fp8(
                        af[mi].x, bfm[ni].x, acc[mi][ni], 0, 0, 0);
                    acc[mi][ni] = __builtin_amdgcn_mfma_f32_16x16x32_fp8_fp8(
                        af[mi].y, bfm[ni].y, acc[mi][ni], 0, 0, 0);
                }
        }

        // ============== per-wave compaction epilogue (strict j>i) ===========
        __syncthreads();             // tile reads done: overlay list on As
        unsigned short* wl = (unsigned short*)As + wave * 2048;
        int base = 0;
        // C/D layout: col = lane&15, row = quad*4 + reg
#pragma unroll
        for (int mi = 0; mi < 4; mi++) {
#pragma unroll
            for (int ni = 0; ni < 4; ni++) {
#pragma unroll
                for (int r = 0; r < 4; r++) {
                    int il = wrg * 64 + mi * 16 + quad * 4 + r;  // 0..255
                    int jl = wcg * 64 + ni * 16 + l16;           // 0..127
                    bool msk = (acc[mi][ni][r] > SIM_THR) && (rowJ + jl > rowI + il);
                    unsigned long long bal = __ballot(msk);
                    if (msk) {
                        int pos = base + __popcll(bal & ((1ull << lane) - 1ull));
                        if (pos < 2048) wl[pos] = (unsigned short)((il << 7) | jl);
                    }
                    base += __popcll(bal);
                }
            }
        }
        if (base > 2048) base = 2048;   // safety clamp (expected ~64/wave)

        for (int t = lane; t < base; t += 64) {
            int e = wl[t];
            int i = rowI + (e >> 7), j = rowJ + (e & 127);
            const float4* Li4 = (const float4*)(Lm + i * E_SZ);
            const float4* Pj4 = (const float4*)(Pm + j * E_SZ);
            const float4* Lj4 = (const float4*)(Lm + j * E_SZ);
            const float4* Pi4 = (const float4*)(Pm + i * E_SZ);
            float d = 0.f, d2 = 0.f;
#pragma unroll
            for (int q = 0; q < 4; q++) {
                float4 a = Li4[q], bb = Pj4[q];
                d += a.x * bb.x + a.y * bb.y + a.z * bb.z + a.w * bb.w;
                float4 a2 = Lj4[q], b2 = Pi4[q];
                d2 += a2.x * b2.x + a2.y * b2.y + a2.z * b2.z + a2.w * b2.w;
            }
            fsum += (ne[j] - d) + (ne[i] - d2);
            lcnt += 2;
        }
    }

#pragma unroll
    for (int off = 32; off > 0; off >>= 1) {
        fsum += __shfl_down(fsum, off, 64);
        lcnt += __shfl_down(lcnt, off, 64);
    }
    if (lane == 0) { redf[wave] = fsum; redc[wave] = lcnt; }
    __syncthreads();
    if (tid == 0) {
        float sv = 0.f;
        unsigned int c = 0u;
#pragma unroll
        for (int w = 0; w < 8; w++) { sv += redf[w]; c += redc[w]; }
        if (c > 0u) {
            atomicAdd(gsum, sv);
            atomicAdd(gcnt, c);
        }
        __threadfence();                       // make accumulators visible
        unsigned int old = atomicAdd(done, 1u);
        if (old == gridDim.x - 1) {            // last block finalizes
            float S = atomicAdd(gsum, 0.0f);   // device-scope atomic read
            unsigned int C = atomicAdd(gcnt, 0u);
            out[0] = (C > 0u) ? (S / (float)C) : 0.f;   // WEIGHT = 1.0
        }
    }
}

// ---------------------------------------------------------------------------
extern "C" void kernel_launch(void* const* d_in, const int* in_sizes, int n_in,
                              void* d_out, int out_size, void* d_ws, size_t ws_size,
                              hipStream_t stream) {
    const float* rp  = (const float*)d_in[0];
    const float* emb = (const float*)d_in[1];
    float* out = (float*)d_out;

    char* ws = (char*)d_ws;
    float*         gsum = (float*)(ws + 0);
    unsigned int*  gcnt = (unsigned int*)(ws + 4);
    unsigned int*  done = (unsigned int*)(ws + 8);
    float*         ne   = (float*)(ws + OFF_NE);
    float*         Lm   = (float*)(ws + OFF_L);
    float*         Pm   = (float*)(ws + OFF_P);
    unsigned char* embL = (unsigned char*)(ws + OFF_EMB);

    prep_kernel<<<2048 + 32, 256, 0, stream>>>(rp, emb, embL, Lm, Pm, ne, gsum, gcnt, done);
    sim_kl_kernel<<<8 * GRID_PER_XCD, 512, 0, stream>>>(embL, Lm, Pm, ne, gsum, gcnt, done, out);
}